// Round 2
// baseline (322.881 us; speedup 1.0000x reference)
//
#include <hip/hip_runtime.h>

#define BATCH 512
#define T 256
#define C 384
#define H 64

typedef __bf16 bf16x8 __attribute__((ext_vector_type(8)));
typedef __bf16 bf16x4 __attribute__((ext_vector_type(4)));
typedef float f32x4 __attribute__((ext_vector_type(4)));

// LDS byte map (total 80 KB -> 2 blocks/CU).
// Phase 1: Xs @0 (32KB): [256][64] bf16, row stride 128B, swizzle ^((t&7)<<4)
//          (fallback only) Ws @32768 (24KB): 3 x [64h][64k] bf16 W^T, same swizzle
// Phase 2: Ks @0 ([256][64] bf16 row-major, swizzled)  [overlaps Xs, barrier-separated]
//          VT @32768 ([64h][256t] bf16, row stride 512B, swizzle ^((h&7)<<4))
//          SCR @65536: 8 waves x 2KB: Q-tile [16][64] stride 128B swz ^((row&7)<<4),
//                      reused for P-stage [16][32] stride 64B swz ^((row&3)<<4)
#define XS_OFF 0
#define KS_OFF 0
#define WS_OFF 32768
#define VT_OFF 32768
#define SCR_OFF 65536
#define LDS_BYTES 81920

__global__ void transpose_w(const float* __restrict__ Wq, const float* __restrict__ Wk,
                            const float* __restrict__ Wv, __bf16* __restrict__ wT) {
    const int i = blockIdx.x * 256 + threadIdx.x;   // [3][64 h][384 c]
    if (i >= 3 * H * C) return;
    const int c = i % C;
    const int h = (i / C) % H;
    const int m = i / (C * H);
    const float* W = (m == 0) ? Wq : (m == 1) ? Wk : Wv;
    wT[i] = (__bf16)W[c * H + h];
}

template <bool USE_WT>
__global__ __launch_bounds__(512, 4) void head_fused(
    const float* __restrict__ x, const float* __restrict__ Wq,
    const float* __restrict__ Wk, const float* __restrict__ Wv,
    const __bf16* __restrict__ wT, float* __restrict__ out)
{
    __shared__ __align__(16) unsigned char lds[LDS_BYTES];
    const int tid  = threadIdx.x;
    const int w    = tid >> 6;
    const int lane = tid & 63;
    const int l15  = lane & 15;
    const int g    = lane >> 4;
    const int b    = blockIdx.x;
    const float* xb = x + (size_t)b * T * C;
    const float* wm[3] = {Wq, Wk, Wv};

    // q-tile assignment {w, 15-w}: balances causal work across waves in phase 2.
    const int tile0 = w;
    const int tile1 = 15 - w;

    // ---------------- Phase 1: projections Q,K,V = X * W ----------------
    f32x4 acc[3][2][4];
#pragma unroll
    for (int m = 0; m < 3; ++m)
#pragma unroll
        for (int j = 0; j < 2; ++j)
#pragma unroll
            for (int n = 0; n < 4; ++n)
                acc[m][j][n] = (f32x4){0.f, 0.f, 0.f, 0.f};

    for (int kt = 0; kt < 6; ++kt) {
        // stage X[:, kt*64 .. +64) -> Xs (bf16, swizzled)
        {
            const int c0 = (tid & 7) << 3;
#pragma unroll
            for (int it = 0; it < 4; ++it) {
                const int t = (tid >> 3) + (it << 6);
                const float* src = xb + t * C + kt * 64 + c0;
                const float4 f0 = *reinterpret_cast<const float4*>(src);
                const float4 f1 = *reinterpret_cast<const float4*>(src + 4);
                bf16x8 v;
                v[0] = (__bf16)f0.x; v[1] = (__bf16)f0.y; v[2] = (__bf16)f0.z; v[3] = (__bf16)f0.w;
                v[4] = (__bf16)f1.x; v[5] = (__bf16)f1.y; v[6] = (__bf16)f1.z; v[7] = (__bf16)f1.w;
                const int off = XS_OFF + t * 128 + ((c0 * 2) ^ ((t & 7) << 4));
                *reinterpret_cast<bf16x8*>(lds + off) = v;
            }
        }
        if (!USE_WT) {
            // fallback: stage W^T tiles in LDS
            const int k  = tid >> 3;
            const int h0 = (tid & 7) << 3;
#pragma unroll
            for (int m = 0; m < 3; ++m) {
                const float* src = wm[m] + (kt * 64 + k) * H + h0;
                const float4 f0 = *reinterpret_cast<const float4*>(src);
                const float4 f1 = *reinterpret_cast<const float4*>(src + 4);
                const float vals[8] = {f0.x, f0.y, f0.z, f0.w, f1.x, f1.y, f1.z, f1.w};
#pragma unroll
                for (int jj = 0; jj < 8; ++jj) {
                    const int hr  = h0 + jj;
                    const int off = WS_OFF + m * 8192 + hr * 128 + ((2 * k) ^ ((hr & 7) << 4));
                    *reinterpret_cast<__bf16*>(lds + off) = (__bf16)vals[jj];
                }
            }
        }
        __syncthreads();

        bf16x8 af[2][2];
#pragma unroll
        for (int j = 0; j < 2; ++j) {
            const int row = ((j == 0) ? tile0 : tile1) * 16 + l15;
#pragma unroll
            for (int ks = 0; ks < 2; ++ks) {
                const int off = XS_OFF + row * 128 + (((ks << 6) + (g << 4)) ^ ((row & 7) << 4));
                af[j][ks] = *reinterpret_cast<const bf16x8*>(lds + off);
            }
        }
#pragma unroll
        for (int m = 0; m < 3; ++m) {
#pragma unroll
            for (int n = 0; n < 4; ++n) {
                const int brow = (n << 4) + l15;
#pragma unroll
                for (int ks = 0; ks < 2; ++ks) {
                    bf16x8 bfr;
                    if (USE_WT) {
                        bfr = *reinterpret_cast<const bf16x8*>(
                            wT + (size_t)(m * 64 + brow) * C + kt * 64 + ks * 32 + g * 8);
                    } else {
                        const int off = WS_OFF + m * 8192 + brow * 128 +
                                        (((ks << 6) + (g << 4)) ^ ((brow & 7) << 4));
                        bfr = *reinterpret_cast<const bf16x8*>(lds + off);
                    }
#pragma unroll
                    for (int j = 0; j < 2; ++j)
                        acc[m][j][n] = __builtin_amdgcn_mfma_f32_16x16x32_bf16(af[j][ks], bfr, acc[m][j][n], 0, 0, 0);
                }
            }
        }
        __syncthreads();
    }

    // epilogue: K row-major @KS, V^T @VT (packed b64 writes); Q stays in registers.
#pragma unroll
    for (int j = 0; j < 2; ++j) {
        const int tb = ((j == 0) ? tile0 : tile1) * 16;
#pragma unroll
        for (int n = 0; n < 4; ++n) {
            const int hcol = (n << 4) + l15;
            // V^T: 4 consecutive t per lane -> packed 8B write
            bf16x4 pv;
#pragma unroll
            for (int r = 0; r < 4; ++r) pv[r] = (__bf16)acc[2][j][n][r];
            const int trow0 = tb + (g << 2);
            *reinterpret_cast<bf16x4*>(lds + VT_OFF + hcol * 512 + ((2 * trow0) ^ ((hcol & 7) << 4))) = pv;
            // K: row-major scalar writes
#pragma unroll
            for (int r = 0; r < 4; ++r) {
                const int trow = tb + (g << 2) + r;
                *reinterpret_cast<__bf16*>(lds + KS_OFF + trow * 128 + ((2 * hcol) ^ ((trow & 7) << 4))) =
                    (__bf16)acc[1][j][n][r];
            }
        }
    }
    __syncthreads();

    // ---------------- Phase 2: causal attention ----------------
    const float scale = 0.051031036307982884f;  // 384^-0.5
#pragma unroll 1
    for (int hf = 0; hf < 2; ++hf) {
        const int mt  = (hf == 0) ? tile0 : tile1;
        const int mtu = __builtin_amdgcn_readfirstlane(mt);
        const int q0  = mt << 4;
        unsigned char* scr = lds + SCR_OFF + (w << 11);

        // stage own Q tile from registers (wave-local; no barrier needed)
#pragma unroll
        for (int n = 0; n < 4; ++n)
#pragma unroll
            for (int r = 0; r < 4; ++r) {
                const int row = (g << 2) + r, col = (n << 4) + l15;
                *reinterpret_cast<__bf16*>(scr + row * 128 + ((2 * col) ^ ((row & 7) << 4))) =
                    (__bf16)acc[0][hf][n][r];
            }
        bf16x8 qf[2];
#pragma unroll
        for (int ks = 0; ks < 2; ++ks)
            qf[ks] = *reinterpret_cast<const bf16x8*>(
                scr + l15 * 128 + (((ks << 6) + (g << 4)) ^ ((l15 & 7) << 4)));

        f32x4 s[16];
#pragma unroll
        for (int n = 0; n < 16; ++n) s[n] = (f32x4){0.f, 0.f, 0.f, 0.f};
#pragma unroll
        for (int n = 0; n < 16; ++n) {
            if (n <= mtu) {     // causal skip (wave-uniform)
                const int brow = (n << 4) + l15;
#pragma unroll
                for (int ks = 0; ks < 2; ++ks) {
                    const bf16x8 bfr = *reinterpret_cast<const bf16x8*>(
                        lds + KS_OFF + brow * 128 + (((ks << 6) + (g << 4)) ^ ((brow & 7) << 4)));
                    s[n] = __builtin_amdgcn_mfma_f32_16x16x32_bf16(qf[ks], bfr, s[n], 0, 0, 0);
                }
            }
        }

        float mrow[4] = {-1e30f, -1e30f, -1e30f, -1e30f};
#pragma unroll
        for (int n = 0; n < 16; ++n) {
            if (n <= mtu) {
#pragma unroll
                for (int r = 0; r < 4; ++r) {
                    float v = s[n][r] * scale;
                    if ((n << 4) + l15 > q0 + (g << 2) + r) v = -1e30f;
                    s[n][r] = v;
                    mrow[r] = fmaxf(mrow[r], v);
                }
            }
        }
#pragma unroll
        for (int d = 1; d < 16; d <<= 1)
#pragma unroll
            for (int r = 0; r < 4; ++r)
                mrow[r] = fmaxf(mrow[r], __shfl_xor(mrow[r], d));

        float ssum[4] = {0.f, 0.f, 0.f, 0.f};
#pragma unroll
        for (int n = 0; n < 16; ++n) {
            if (n <= mtu) {
#pragma unroll
                for (int r = 0; r < 4; ++r) {
                    const float p = __expf(s[n][r] - mrow[r]);
                    s[n][r] = p;
                    ssum[r] += p;
                }
            }
        }
#pragma unroll
        for (int d = 1; d < 16; d <<= 1)
#pragma unroll
            for (int r = 0; r < 4; ++r)
                ssum[r] += __shfl_xor(ssum[r], d);

        // PV: stage unnormalized P chunks (16q x 32k) through per-wave scratch
        f32x4 o[4];
#pragma unroll
        for (int nh = 0; nh < 4; ++nh) o[nh] = (f32x4){0.f, 0.f, 0.f, 0.f};
#pragma unroll
        for (int cc = 0; cc < 8; ++cc) {
            if (cc <= (mtu >> 1)) {   // causal skip; s[] of skipped halves is exactly 0
#pragma unroll
                for (int hn = 0; hn < 2; ++hn) {
                    const int n = 2 * cc + hn;
#pragma unroll
                    for (int r = 0; r < 4; ++r) {
                        const int prow = (g << 2) + r;
                        const int pcol = (hn << 4) + l15;
                        *reinterpret_cast<__bf16*>(
                            scr + prow * 64 + ((2 * pcol) ^ ((prow & 3) << 4))) = (__bf16)s[n][r];
                    }
                }
                const bf16x8 pf = *reinterpret_cast<const bf16x8*>(
                    scr + l15 * 64 + ((g << 4) ^ ((l15 & 3) << 4)));
#pragma unroll
                for (int nh = 0; nh < 4; ++nh) {
                    const int hrow = (nh << 4) + l15;
                    const bf16x8 vf = *reinterpret_cast<const bf16x8*>(
                        lds + VT_OFF + hrow * 512 + (((cc << 6) + (g << 4)) ^ ((hrow & 7) << 4)));
                    o[nh] = __builtin_amdgcn_mfma_f32_16x16x32_bf16(pf, vf, o[nh], 0, 0, 0);
                }
            }
        }

        float inv[4];
#pragma unroll
        for (int r = 0; r < 4; ++r) inv[r] = 1.0f / ssum[r];
        float* ob = out + ((size_t)b * T + q0) * H;
#pragma unroll
        for (int nh = 0; nh < 4; ++nh)
#pragma unroll
            for (int r = 0; r < 4; ++r)
                ob[((g << 2) + r) * H + (nh << 4) + l15] = o[nh][r] * inv[r];
    }
}

extern "C" void kernel_launch(void* const* d_in, const int* in_sizes, int n_in,
                              void* d_out, int out_size, void* d_ws, size_t ws_size,
                              hipStream_t stream) {
    (void)in_sizes; (void)n_in; (void)out_size;
    const float* x  = (const float*)d_in[0];
    const float* Wk = (const float*)d_in[1];
    const float* Wq = (const float*)d_in[2];
    const float* Wv = (const float*)d_in[3];
    float* out = (float*)d_out;
    const size_t wt_bytes = (size_t)3 * H * C * sizeof(__bf16);
    if (ws_size >= wt_bytes) {
        __bf16* wT = (__bf16*)d_ws;
        transpose_w<<<dim3((3 * H * C + 255) / 256), dim3(256), 0, stream>>>(Wq, Wk, Wv, wT);
        head_fused<true><<<dim3(BATCH), dim3(512), 0, stream>>>(x, Wq, Wk, Wv, wT, out);
    } else {
        head_fused<false><<<dim3(BATCH), dim3(512), 0, stream>>>(x, Wq, Wk, Wv, nullptr, out);
    }
}

// Round 3
// 85.463 us; speedup vs baseline: 3.7780x; 3.7780x over previous
//
#include <hip/hip_runtime.h>

#define BATCH 512
#define T 256
#define C 384
#define H 64

typedef __bf16 bf16x8 __attribute__((ext_vector_type(8)));
typedef __bf16 bf16x4 __attribute__((ext_vector_type(4)));
typedef float f32x4 __attribute__((ext_vector_type(4)));

// LDS byte map (80 KB total -> 2 blocks/CU).
// Phase 1: Xs @0 (32KB): [256 t][64 c] bf16, row stride 128B, swizzle ^((t&7)<<4)
// Phase 2: Ks @0 (overlaps Xs, barrier-separated): [256 t][64 h] bf16, same swizzle
//          VT @32768 (32KB): [64 h][256 t] bf16, row stride 512B, swizzle ^((h&7)<<4)
//          SCR @65536: 8 waves x 2KB: [16][64] bf16 stride 128B swz ^((row&7)<<4)
//                      (Q-transpose at epilogue, then P staging in phase 2)
#define XS_OFF 0
#define KS_OFF 0
#define VT_OFF 32768
#define SCR_OFF 65536
#define LDS_BYTES 81920

// wT layout: MFMA B-fragments in lane order. frag fi = ((kt*2+ks)*3+m)*4+n,
// element block fi*512 + lane*8; lane(l15,g) holds W^T[h=n*16+l15][k=kt*64+ks*32+g*8 ..+8].
__global__ void prep_w(const float* __restrict__ Wq, const float* __restrict__ Wk,
                       const float* __restrict__ Wv, __bf16* __restrict__ wT) {
    const int tid = blockIdx.x * 256 + threadIdx.x;   // 9216 threads
    if (tid >= 9216) return;
    const int lane = tid & 63;
    const int f    = tid >> 6;        // 0..143
    const int n    = f & 3;
    const int f2   = f >> 2;          // kk*3 + m
    const int m    = f2 % 3;
    const int kk   = f2 / 3;          // kt*2+ks, 0..11
    const int l15  = lane & 15;
    const int g    = lane >> 4;
    const int h    = n * 16 + l15;
    const int k0   = kk * 32 + g * 8;
    const float* W = (m == 0) ? Wq : (m == 1) ? Wk : Wv;
    bf16x8 v;
#pragma unroll
    for (int j = 0; j < 8; ++j) v[j] = (__bf16)W[(k0 + j) * H + h];
    reinterpret_cast<bf16x8*>(wT)[tid] = v;
}

template <bool USE_WT>
__global__ __launch_bounds__(512, 4) void head_fused(
    const float* __restrict__ x, const float* __restrict__ Wq,
    const float* __restrict__ Wk, const float* __restrict__ Wv,
    const __bf16* __restrict__ wT, float* __restrict__ out)
{
    __shared__ __align__(16) unsigned char lds[LDS_BYTES];
    const int tid  = threadIdx.x;
    const int w    = tid >> 6;
    const int lane = tid & 63;
    const int l15  = lane & 15;
    const int g    = lane >> 4;
    const int b    = blockIdx.x;
    const float* xb = x + (size_t)b * T * C;
    const float* wm[3] = {Wq, Wk, Wv};

    const int tile0 = w;          // phase-2 causal balance: chunks(w)+chunks(15-w)==5 for all w
    const int tile1 = 15 - w;

    // ---------------- Phase 1: Q,K,V = X * W ----------------
    f32x4 acc[3][2][4];
#pragma unroll
    for (int m = 0; m < 3; ++m)
#pragma unroll
        for (int j = 0; j < 2; ++j)
#pragma unroll
            for (int n = 0; n < 4; ++n)
                acc[m][j][n] = (f32x4){0.f, 0.f, 0.f, 0.f};

#pragma unroll 1
    for (int kt = 0; kt < 6; ++kt) {
        // stage X[:, kt*64..+64) -> Xs (bf16, swizzled)
        {
            const int c0 = (tid & 7) << 3;
#pragma unroll
            for (int it = 0; it < 4; ++it) {
                const int t = (tid >> 3) + (it << 6);
                const float* src = xb + t * C + kt * 64 + c0;
                const float4 f0 = *reinterpret_cast<const float4*>(src);
                const float4 f1 = *reinterpret_cast<const float4*>(src + 4);
                bf16x8 v;
                v[0] = (__bf16)f0.x; v[1] = (__bf16)f0.y; v[2] = (__bf16)f0.z; v[3] = (__bf16)f0.w;
                v[4] = (__bf16)f1.x; v[5] = (__bf16)f1.y; v[6] = (__bf16)f1.z; v[7] = (__bf16)f1.w;
                const int off = XS_OFF + t * 128 + ((c0 * 2) ^ ((t & 7) << 4));
                *reinterpret_cast<bf16x8*>(lds + off) = v;
            }
        }
        __syncthreads();

#pragma unroll
        for (int ks = 0; ks < 2; ++ks) {
            bf16x8 af0, af1;
            {
                const int r0 = tile0 * 16 + l15;
                const int r1 = tile1 * 16 + l15;
                af0 = *reinterpret_cast<const bf16x8*>(
                    lds + XS_OFF + r0 * 128 + (((ks << 6) + (g << 4)) ^ ((r0 & 7) << 4)));
                af1 = *reinterpret_cast<const bf16x8*>(
                    lds + XS_OFF + r1 * 128 + (((ks << 6) + (g << 4)) ^ ((r1 & 7) << 4)));
            }
#pragma unroll
            for (int m = 0; m < 3; ++m) {
#pragma unroll
                for (int n = 0; n < 4; ++n) {
                    bf16x8 bfr;
                    if (USE_WT) {
                        const int fi = ((kt * 2 + ks) * 3 + m) * 4 + n;
                        bfr = reinterpret_cast<const bf16x8*>(wT)[fi * 64 + lane];
                    } else {
                        // fallback gather (slow, correctness only)
#pragma unroll
                        for (int j = 0; j < 8; ++j)
                            bfr[j] = (__bf16)wm[m][(kt * 64 + ks * 32 + g * 8 + j) * H + n * 16 + l15];
                    }
                    acc[m][0][n] = __builtin_amdgcn_mfma_f32_16x16x32_bf16(af0, bfr, acc[m][0][n], 0, 0, 0);
                    acc[m][1][n] = __builtin_amdgcn_mfma_f32_16x16x32_bf16(af1, bfr, acc[m][1][n], 0, 0, 0);
                }
            }
        }
        __syncthreads();
    }

    // ---------------- epilogue: K->KS, V^T->VT, Q->bf16 frags ----------------
#pragma unroll
    for (int j = 0; j < 2; ++j) {
        const int tb = ((j == 0) ? tile0 : tile1) << 4;
#pragma unroll
        for (int n = 0; n < 4; ++n) {
            const int hcol = (n << 4) + l15;
            bf16x4 pv;
#pragma unroll
            for (int r = 0; r < 4; ++r) pv[r] = (__bf16)acc[2][j][n][r];
            const int trow0 = tb + (g << 2);
            *reinterpret_cast<bf16x4*>(lds + VT_OFF + hcol * 512 + ((2 * trow0) ^ ((hcol & 7) << 4))) = pv;
#pragma unroll
            for (int r = 0; r < 4; ++r) {
                const int trow = tb + (g << 2) + r;
                *reinterpret_cast<__bf16*>(lds + KS_OFF + trow * 128 + ((2 * hcol) ^ ((trow & 7) << 4))) =
                    (__bf16)acc[1][j][n][r];
            }
        }
    }
    unsigned char* scr = lds + SCR_OFF + (w << 11);
    bf16x8 qf0a, qf0b, qf1a, qf1b;   // Q A-frags for tile0/tile1, k-halves a/b
#pragma unroll
    for (int j = 0; j < 2; ++j) {
#pragma unroll
        for (int n = 0; n < 4; ++n)
#pragma unroll
            for (int r = 0; r < 4; ++r) {
                const int row = (g << 2) + r;
                *reinterpret_cast<__bf16*>(
                    scr + row * 128 + ((2 * ((n << 4) + l15)) ^ ((row & 7) << 4))) =
                    (__bf16)acc[0][j][n][r];
            }
        const bf16x8 qa = *reinterpret_cast<const bf16x8*>(
            scr + l15 * 128 + (((g << 4) + 0) ^ ((l15 & 7) << 4)));
        const bf16x8 qb = *reinterpret_cast<const bf16x8*>(
            scr + l15 * 128 + (((g << 4) + 64) ^ ((l15 & 7) << 4)));
        if (j == 0) { qf0a = qa; qf0b = qb; } else { qf1a = qa; qf1b = qb; }
    }
    __syncthreads();

    // ---------------- Phase 2: causal attention (no barriers) ----------------
    const float se = 0.051031036307982884f * 1.4426950408889634f;  // 384^-0.5 * log2(e)

    auto attend = [&](int mt, bf16x8 qfa, bf16x8 qfb) {
        const int mtu = __builtin_amdgcn_readfirstlane(mt);
        const int q0  = mt << 4;
        const int qrow = q0 + (g << 2);

        f32x4 o[4];
#pragma unroll
        for (int nh = 0; nh < 4; ++nh) o[nh] = (f32x4){0.f, 0.f, 0.f, 0.f};
        float ssum[4] = {0.f, 0.f, 0.f, 0.f};

#pragma unroll
        for (int kc = 0; kc < 4; ++kc) {
            if (kc <= (mtu >> 2)) {     // wave-uniform causal skip
                f32x4 sb[4];
#pragma unroll
                for (int n4 = 0; n4 < 4; ++n4) sb[n4] = (f32x4){0.f, 0.f, 0.f, 0.f};
#pragma unroll
                for (int ks4 = 0; ks4 < 2; ++ks4) {
                    const bf16x8 qf = (ks4 == 0) ? qfa : qfb;
#pragma unroll
                    for (int n4 = 0; n4 < 4; ++n4) {
                        const int brow = (kc << 6) + (n4 << 4) + l15;
                        const bf16x8 bfr = *reinterpret_cast<const bf16x8*>(
                            lds + KS_OFF + brow * 128 + (((ks4 << 6) + (g << 4)) ^ ((brow & 7) << 4)));
                        sb[n4] = __builtin_amdgcn_mfma_f32_16x16x32_bf16(qf, bfr, sb[n4], 0, 0, 0);
                    }
                }
                // p = exp(s*scale) (no max-sub: normalization cancels; |s*scale| small), mask, stage
#pragma unroll
                for (int n4 = 0; n4 < 4; ++n4) {
                    const int k = (kc << 6) + (n4 << 4) + l15;
#pragma unroll
                    for (int r = 0; r < 4; ++r) {
                        float p = exp2f(sb[n4][r] * se);
                        if (k > qrow + r) p = 0.f;
                        ssum[r] += p;
                        const int prow = (g << 2) + r;
                        *reinterpret_cast<__bf16*>(
                            scr + prow * 128 + ((2 * ((n4 << 4) + l15)) ^ ((prow & 7) << 4))) = (__bf16)p;
                    }
                }
#pragma unroll
                for (int ks4 = 0; ks4 < 2; ++ks4) {
                    const bf16x8 pf = *reinterpret_cast<const bf16x8*>(
                        scr + l15 * 128 + (((ks4 << 6) + (g << 4)) ^ ((l15 & 7) << 4)));
#pragma unroll
                    for (int nh = 0; nh < 4; ++nh) {
                        const int hrow = (nh << 4) + l15;
                        const bf16x8 vb = *reinterpret_cast<const bf16x8*>(
                            lds + VT_OFF + hrow * 512 +
                            (((kc << 7) + (ks4 << 6) + (g << 4)) ^ ((hrow & 7) << 4)));
                        o[nh] = __builtin_amdgcn_mfma_f32_16x16x32_bf16(pf, vb, o[nh], 0, 0, 0);
                    }
                }
            }
        }

#pragma unroll
        for (int d = 1; d < 16; d <<= 1)
#pragma unroll
            for (int r = 0; r < 4; ++r)
                ssum[r] += __shfl_xor(ssum[r], d);

        float inv[4];
#pragma unroll
        for (int r = 0; r < 4; ++r) inv[r] = 1.0f / ssum[r];
        float* ob = out + ((size_t)b * T + q0) * H;
#pragma unroll
        for (int nh = 0; nh < 4; ++nh)
#pragma unroll
            for (int r = 0; r < 4; ++r)
                ob[((g << 2) + r) * H + (nh << 4) + l15] = o[nh][r] * inv[r];
    };

    attend(tile0, qf0a, qf0b);
    attend(tile1, qf1a, qf1b);
}

extern "C" void kernel_launch(void* const* d_in, const int* in_sizes, int n_in,
                              void* d_out, int out_size, void* d_ws, size_t ws_size,
                              hipStream_t stream) {
    (void)in_sizes; (void)n_in; (void)out_size;
    const float* x  = (const float*)d_in[0];
    const float* Wk = (const float*)d_in[1];
    const float* Wq = (const float*)d_in[2];
    const float* Wv = (const float*)d_in[3];
    float* out = (float*)d_out;
    const size_t wt_bytes = (size_t)9216 * 8 * sizeof(__bf16);
    if (ws_size >= wt_bytes) {
        __bf16* wT = (__bf16*)d_ws;
        prep_w<<<dim3(36), dim3(256), 0, stream>>>(Wq, Wk, Wv, wT);
        head_fused<true><<<dim3(BATCH), dim3(512), 0, stream>>>(x, Wq, Wk, Wv, wT, out);
    } else {
        head_fused<false><<<dim3(BATCH), dim3(512), 0, stream>>>(x, Wq, Wk, Wv, nullptr, out);
    }
}

// Round 4
// 83.472 us; speedup vs baseline: 3.8682x; 1.0239x over previous
//
#include <hip/hip_runtime.h>

#define BATCH 512
#define T 256
#define C 384
#define H 64

typedef __bf16 bf16x8 __attribute__((ext_vector_type(8)));
typedef __bf16 bf16x4 __attribute__((ext_vector_type(4)));
typedef float f32x4 __attribute__((ext_vector_type(4)));

// LDS byte map (96 KB, no overlaps, ONE barrier total).
// Ks  @0     (32KB): [256 t][64 h] bf16, row stride 128B, swizzle ^((t&7)<<4)
// VT  @32768 (32KB): [64 h][256 t] bf16, row stride 512B, swizzle ^((h&7)<<4)
// SCR @65536 (32KB): 16 waves x 2KB: [16][64] bf16 stride 128B swz ^((row&7)<<4)
//                    (Q-transpose at epilogue, then P staging in phase 2; wave-local)
#define KS_OFF 0
#define VT_OFF 32768
#define SCR_OFF 65536
#define LDS_BYTES 98304

// wT layout: MFMA B-fragments in lane order. frag fi = ((kt*2+ks)*3+m)*4+n,
// 64 lanes x 16B each; lane(l15,g) holds W^T[h=n*16+l15][k=kt*64+ks*32+g*8 ..+8].
__global__ void prep_w(const float* __restrict__ Wq, const float* __restrict__ Wk,
                       const float* __restrict__ Wv, __bf16* __restrict__ wT) {
    const int tid = blockIdx.x * 256 + threadIdx.x;   // 9216 threads
    if (tid >= 9216) return;
    const int lane = tid & 63;
    const int f    = tid >> 6;        // 0..143
    const int n    = f & 3;
    const int f2   = f >> 2;          // kk*3 + m
    const int m    = f2 % 3;
    const int kk   = f2 / 3;          // kt*2+ks, 0..11
    const int l15  = lane & 15;
    const int g    = lane >> 4;
    const int h    = n * 16 + l15;
    const int k0   = kk * 32 + g * 8;
    const float* W = (m == 0) ? Wq : (m == 1) ? Wk : Wv;
    bf16x8 v;
#pragma unroll
    for (int j = 0; j < 8; ++j) v[j] = (__bf16)W[(k0 + j) * H + h];
    reinterpret_cast<bf16x8*>(wT)[tid] = v;
}

template <bool USE_WT>
__global__ __launch_bounds__(1024, 4) void head_fused(
    const float* __restrict__ x, const float* __restrict__ Wq,
    const float* __restrict__ Wk, const float* __restrict__ Wv,
    const __bf16* __restrict__ wT, float* __restrict__ out)
{
    __shared__ __align__(16) unsigned char lds[LDS_BYTES];
    const int tid  = threadIdx.x;
    const int w    = tid >> 6;        // wave 0..15 == q-tile index
    const int lane = tid & 63;
    const int l15  = lane & 15;
    const int g    = lane >> 4;
    const int b    = blockIdx.x;
    const float* wm[3] = {Wq, Wk, Wv};

    // ---------------- Phase 1: Q,K,V rows [w*16, w*16+16) = X * W ----------------
    // A-fragments straight from global (no LDS, no barriers): lane(l15,g) reads
    // x[row = w*16+l15][kt*64 + ks*32 + g*8 .. +8) — 64-B lines fully consumed.
    const float* xrow = x + (size_t)b * T * C + ((w << 4) + l15) * C;

    f32x4 acc[3][4];
#pragma unroll
    for (int m = 0; m < 3; ++m)
#pragma unroll
        for (int n = 0; n < 4; ++n)
            acc[m][n] = (f32x4){0.f, 0.f, 0.f, 0.f};

    float4 pre[4];   // software pipeline: next kt's 16 floats per lane
#pragma unroll
    for (int q = 0; q < 4; ++q)
        pre[q] = *reinterpret_cast<const float4*>(xrow + ((q >> 1) << 5) + (g << 3) + ((q & 1) << 2));

#pragma unroll 1
    for (int kt = 0; kt < 6; ++kt) {
        bf16x8 af[2];
#pragma unroll
        for (int ks = 0; ks < 2; ++ks)
#pragma unroll
            for (int j = 0; j < 8; ++j)
                af[ks][j] = (__bf16)((j < 4) ? pre[ks * 2][j] : pre[ks * 2 + 1][j - 4]);
        if (kt < 5) {
            const float* nxt = xrow + (kt + 1) * 64;
#pragma unroll
            for (int q = 0; q < 4; ++q)
                pre[q] = *reinterpret_cast<const float4*>(nxt + ((q >> 1) << 5) + (g << 3) + ((q & 1) << 2));
        }
#pragma unroll
        for (int m = 0; m < 3; ++m) {
#pragma unroll
            for (int n = 0; n < 4; ++n) {
#pragma unroll
                for (int ks = 0; ks < 2; ++ks) {
                    bf16x8 bfr;
                    if (USE_WT) {
                        const int fi = ((kt * 2 + ks) * 3 + m) * 4 + n;
                        bfr = reinterpret_cast<const bf16x8*>(wT)[fi * 64 + lane];
                    } else {
#pragma unroll
                        for (int j = 0; j < 8; ++j)
                            bfr[j] = (__bf16)wm[m][(kt * 64 + ks * 32 + g * 8 + j) * H + n * 16 + l15];
                    }
                    acc[m][n] = __builtin_amdgcn_mfma_f32_16x16x32_bf16(af[ks], bfr, acc[m][n], 0, 0, 0);
                }
            }
        }
    }

    // ---------------- epilogue: K->Ks, V^T->VT, Q->bf16 frags via scr ----------------
    // D layout: h = n*16+l15, t(within tile) = g*4+r.
    const int tb = w << 4;
#pragma unroll
    for (int n = 0; n < 4; ++n) {
        const int hcol = (n << 4) + l15;
        bf16x4 pv;
#pragma unroll
        for (int r = 0; r < 4; ++r) pv[r] = (__bf16)acc[2][n][r];
        const int trow0 = tb + (g << 2);
        *reinterpret_cast<bf16x4*>(lds + VT_OFF + hcol * 512 + ((2 * trow0) ^ ((hcol & 7) << 4))) = pv;
#pragma unroll
        for (int r = 0; r < 4; ++r) {
            const int trow = trow0 + r;
            *reinterpret_cast<__bf16*>(lds + KS_OFF + trow * 128 + ((2 * hcol) ^ ((trow & 7) << 4))) =
                (__bf16)acc[1][n][r];
        }
    }
    unsigned char* scr = lds + SCR_OFF + (w << 11);
#pragma unroll
    for (int n = 0; n < 4; ++n)
#pragma unroll
        for (int r = 0; r < 4; ++r) {
            const int row = (g << 2) + r;
            *reinterpret_cast<__bf16*>(
                scr + row * 128 + ((2 * ((n << 4) + l15)) ^ ((row & 7) << 4))) = (__bf16)acc[0][n][r];
        }
    const bf16x8 qfa = *reinterpret_cast<const bf16x8*>(
        scr + l15 * 128 + (((g << 4) + 0) ^ ((l15 & 7) << 4)));
    const bf16x8 qfb = *reinterpret_cast<const bf16x8*>(
        scr + l15 * 128 + (((g << 4) + 64) ^ ((l15 & 7) << 4)));
    __syncthreads();   // the only barrier: Ks/VT now visible to all waves

    // ---------------- Phase 2: causal attention, wave-independent ----------------
    const float se = 0.051031036307982884f * 1.4426950408889634f;  // 384^-0.5 * log2(e)
    const int mtu  = __builtin_amdgcn_readfirstlane(w);
    const int q0   = mtu << 4;
    const int qrow = q0 + (g << 2);

    f32x4 o[4];
#pragma unroll
    for (int nh = 0; nh < 4; ++nh) o[nh] = (f32x4){0.f, 0.f, 0.f, 0.f};
    float ssum[4] = {0.f, 0.f, 0.f, 0.f};

#pragma unroll
    for (int kc = 0; kc < 4; ++kc) {
        if (kc <= (mtu >> 2)) {     // wave-uniform causal skip
            f32x4 sb[4];
#pragma unroll
            for (int n4 = 0; n4 < 4; ++n4) sb[n4] = (f32x4){0.f, 0.f, 0.f, 0.f};
#pragma unroll
            for (int ks4 = 0; ks4 < 2; ++ks4) {
                const bf16x8 qf = (ks4 == 0) ? qfa : qfb;
#pragma unroll
                for (int n4 = 0; n4 < 4; ++n4) {
                    const int brow = (kc << 6) + (n4 << 4) + l15;
                    const bf16x8 bfr = *reinterpret_cast<const bf16x8*>(
                        lds + KS_OFF + brow * 128 + (((ks4 << 6) + (g << 4)) ^ ((brow & 7) << 4)));
                    sb[n4] = __builtin_amdgcn_mfma_f32_16x16x32_bf16(qf, bfr, sb[n4], 0, 0, 0);
                }
            }
            // p = exp(s*scale); no max-sub (normalization cancels, |s*scale| small). mask, stage.
#pragma unroll
            for (int n4 = 0; n4 < 4; ++n4) {
                const int k = (kc << 6) + (n4 << 4) + l15;
#pragma unroll
                for (int r = 0; r < 4; ++r) {
                    float p = exp2f(sb[n4][r] * se);
                    if (k > qrow + r) p = 0.f;
                    ssum[r] += p;
                    const int prow = (g << 2) + r;
                    *reinterpret_cast<__bf16*>(
                        scr + prow * 128 + ((2 * ((n4 << 4) + l15)) ^ ((prow & 7) << 4))) = (__bf16)p;
                }
            }
#pragma unroll
            for (int ks4 = 0; ks4 < 2; ++ks4) {
                const bf16x8 pf = *reinterpret_cast<const bf16x8*>(
                    scr + l15 * 128 + (((ks4 << 6) + (g << 4)) ^ ((l15 & 7) << 4)));
#pragma unroll
                for (int nh = 0; nh < 4; ++nh) {
                    const int hrow = (nh << 4) + l15;
                    const bf16x8 vb = *reinterpret_cast<const bf16x8*>(
                        lds + VT_OFF + hrow * 512 +
                        (((kc << 7) + (ks4 << 6) + (g << 4)) ^ ((hrow & 7) << 4)));
                    o[nh] = __builtin_amdgcn_mfma_f32_16x16x32_bf16(pf, vb, o[nh], 0, 0, 0);
                }
            }
        }
    }

#pragma unroll
    for (int d = 1; d < 16; d <<= 1)
#pragma unroll
        for (int r = 0; r < 4; ++r)
            ssum[r] += __shfl_xor(ssum[r], d);

    float inv[4];
#pragma unroll
    for (int r = 0; r < 4; ++r) inv[r] = 1.0f / ssum[r];
    float* ob = out + ((size_t)b * T + q0) * H;
#pragma unroll
    for (int nh = 0; nh < 4; ++nh)
#pragma unroll
        for (int r = 0; r < 4; ++r)
            ob[((g << 2) + r) * H + (nh << 4) + l15] = o[nh][r] * inv[r];
}

extern "C" void kernel_launch(void* const* d_in, const int* in_sizes, int n_in,
                              void* d_out, int out_size, void* d_ws, size_t ws_size,
                              hipStream_t stream) {
    (void)in_sizes; (void)n_in; (void)out_size;
    const float* x  = (const float*)d_in[0];
    const float* Wk = (const float*)d_in[1];
    const float* Wq = (const float*)d_in[2];
    const float* Wv = (const float*)d_in[3];
    float* out = (float*)d_out;
    const size_t wt_bytes = (size_t)9216 * 8 * sizeof(__bf16);
    if (ws_size >= wt_bytes) {
        __bf16* wT = (__bf16*)d_ws;
        prep_w<<<dim3(36), dim3(256), 0, stream>>>(Wq, Wk, Wv, wT);
        head_fused<true><<<dim3(BATCH), dim3(1024), 0, stream>>>(x, Wq, Wk, Wv, wT, out);
    } else {
        head_fused<false><<<dim3(BATCH), dim3(1024), 0, stream>>>(x, Wq, Wk, Wv, nullptr, out);
    }
}

// Round 5
// 60.870 us; speedup vs baseline: 5.3044x; 1.3713x over previous
//
#include <hip/hip_runtime.h>

#define BATCH 512
#define T 256
#define C 384
#define H 64

typedef __bf16 bf16x8 __attribute__((ext_vector_type(8)));
typedef __bf16 bf16x4 __attribute__((ext_vector_type(4)));
typedef float f32x4 __attribute__((ext_vector_type(4)));

// LDS byte map (80 KB).
// Phase 1 (per kt, barrier-bracketed):
//   XS @0     (32KB): X k-tile [256 t][64 c] bf16, row stride 128B, swz ^((t&7)<<4)
//   WF @32768 (24KB): 24 W B-frags, frag fl at fl*1024 + lane*16 (linear, conflict-free)
// Phase 2 (after epilogue overwrite):
//   Ks @0     (32KB): K [256 t][64 h] bf16, swz ^((t&7)<<4)
//   VT @32768 (32KB): V^T [64 h][256 t] bf16, row stride 512B, swz ^((h&7)<<4)
//   SCR @65536 (16KB): 8 waves x 2KB [16][64] bf16 swz ^((row&7)<<4)  (Q xpose, then P stage)
#define XS_OFF 0
#define KS_OFF 0
#define WF_OFF 32768
#define VT_OFF 32768
#define SCR_OFF 65536
#define LDS_BYTES 81920

// wT layout: MFMA B-fragments in lane order. frag fi = ((kt*2+ks)*3+m)*4+n,
// 64 lanes x 16B; lane(l15,g) holds W^T[h=n*16+l15][k=kt*64+ks*32+g*8 ..+8].
__global__ void prep_w(const float* __restrict__ Wq, const float* __restrict__ Wk,
                       const float* __restrict__ Wv, __bf16* __restrict__ wT) {
    const int tid = blockIdx.x * 256 + threadIdx.x;   // 9216 threads
    if (tid >= 9216) return;
    const int lane = tid & 63;
    const int f    = tid >> 6;        // 0..143
    const int n    = f & 3;
    const int f2   = f >> 2;          // kk*3 + m
    const int m    = f2 % 3;
    const int kk   = f2 / 3;          // kt*2+ks
    const int l15  = lane & 15;
    const int g    = lane >> 4;
    const int h    = n * 16 + l15;
    const int k0   = kk * 32 + g * 8;
    const float* W = (m == 0) ? Wq : (m == 1) ? Wk : Wv;
    bf16x8 v;
#pragma unroll
    for (int j = 0; j < 8; ++j) v[j] = (__bf16)W[(k0 + j) * H + h];
    reinterpret_cast<bf16x8*>(wT)[tid] = v;
}

template <bool USE_WT>
__global__ __launch_bounds__(512, 2) void head_fused(
    const float* __restrict__ x, const float* __restrict__ Wq,
    const float* __restrict__ Wk, const float* __restrict__ Wv,
    const __bf16* __restrict__ wT, float* __restrict__ out)
{
    __shared__ __align__(16) unsigned char lds[LDS_BYTES];
    const int tid  = threadIdx.x;
    const int w    = tid >> 6;
    const int lane = tid & 63;
    const int l15  = lane & 15;
    const int g    = lane >> 4;
    const int b    = blockIdx.x;
    const float* xb = x + (size_t)b * T * C;
    const float* wm[3] = {Wq, Wk, Wv};
    const bf16x8* wTv = reinterpret_cast<const bf16x8*>(wT);

    const int tile0 = w;       // {w, 15-w}: phase-2 causal chunks per pair == 5 for all w
    const int tile1 = 15 - w;

    f32x4 acc[3][2][4];
#pragma unroll
    for (int m = 0; m < 3; ++m)
#pragma unroll
        for (int j = 0; j < 2; ++j)
#pragma unroll
            for (int n = 0; n < 4; ++n)
                acc[m][j][n] = (f32x4){0.f, 0.f, 0.f, 0.f};

    // prefetch registers: X 4 rows x 32B (8 float4), W 3 slots x 16B
    float4 px[8];
    bf16x8 pw[3];
    const int xrow0 = tid >> 3;          // + ri*64
    const int xc0   = (tid & 7) << 3;    // elem col within k-tile

    auto loadX = [&](int kt) {
#pragma unroll
        for (int ri = 0; ri < 4; ++ri) {
            const float* src = xb + (xrow0 + (ri << 6)) * C + kt * 64 + xc0;
            px[2 * ri]     = *reinterpret_cast<const float4*>(src);
            px[2 * ri + 1] = *reinterpret_cast<const float4*>(src + 4);
        }
    };
    auto loadW = [&](int kt) {
        if (USE_WT) {
#pragma unroll
            for (int ri = 0; ri < 3; ++ri)
                pw[ri] = wTv[kt * 1536 + (ri << 9) + tid];
        } else {
#pragma unroll
            for (int ri = 0; ri < 3; ++ri) {
                const int s  = (ri << 9) + tid;   // slot = fl*64 + lane_slot
                const int fl = s >> 6, ls = s & 63;
                const int n = fl & 3, q = fl >> 2, m = q % 3, ks = q / 3;
                const int k0 = kt * 64 + ks * 32 + ((ls >> 4) << 3);
                const int h  = (n << 4) + (ls & 15);
                bf16x8 v;
#pragma unroll
                for (int j = 0; j < 8; ++j) v[j] = (__bf16)wm[m][(k0 + j) * H + h];
                pw[ri] = v;
            }
        }
    };

    loadX(0);
    loadW(0);

#pragma unroll 1
    for (int kt = 0; kt < 6; ++kt) {
        // stage X -> XS (bf16 swizzled), W frags -> WF (linear)
#pragma unroll
        for (int ri = 0; ri < 4; ++ri) {
            const int row = xrow0 + (ri << 6);
            bf16x8 v;
#pragma unroll
            for (int j = 0; j < 8; ++j)
                v[j] = (__bf16)((j < 4) ? px[2 * ri][j] : px[2 * ri + 1][j - 4]);
            *reinterpret_cast<bf16x8*>(
                lds + XS_OFF + row * 128 + ((xc0 * 2) ^ ((row & 7) << 4))) = v;
        }
#pragma unroll
        for (int ri = 0; ri < 3; ++ri)
            *reinterpret_cast<bf16x8*>(lds + WF_OFF + (((ri << 9) + tid) << 4)) = pw[ri];

        if (kt < 5) { loadX(kt + 1); loadW(kt + 1); }   // overlap with barrier+compute
        __syncthreads();

        bf16x8 af[2][2];
#pragma unroll
        for (int j = 0; j < 2; ++j) {
            const int row = ((j == 0) ? tile0 : tile1) * 16 + l15;
#pragma unroll
            for (int ks = 0; ks < 2; ++ks)
                af[j][ks] = *reinterpret_cast<const bf16x8*>(
                    lds + XS_OFF + row * 128 + (((ks << 6) + (g << 4)) ^ ((row & 7) << 4)));
        }
#pragma unroll
        for (int ks = 0; ks < 2; ++ks)
#pragma unroll
            for (int m = 0; m < 3; ++m)
#pragma unroll
                for (int n = 0; n < 4; ++n) {
                    const int fl = ((ks * 3 + m) << 2) + n;
                    const bf16x8 bfr = *reinterpret_cast<const bf16x8*>(
                        lds + WF_OFF + (fl << 10) + (lane << 4));
                    acc[m][0][n] = __builtin_amdgcn_mfma_f32_16x16x32_bf16(af[0][ks], bfr, acc[m][0][n], 0, 0, 0);
                    acc[m][1][n] = __builtin_amdgcn_mfma_f32_16x16x32_bf16(af[1][ks], bfr, acc[m][1][n], 0, 0, 0);
                }
        __syncthreads();   // safe to overwrite XS/WF next kt (or epilogue)
    }

    // ---------------- epilogue: K->Ks, V^T->VT, Q->bf16 frags ----------------
    bf16x8 qf[2][2];   // [tile][k-half]
    unsigned char* scr = lds + SCR_OFF + (w << 11);
#pragma unroll
    for (int j = 0; j < 2; ++j) {
        const int tb = ((j == 0) ? tile0 : tile1) << 4;
#pragma unroll
        for (int n = 0; n < 4; ++n) {
            const int hcol = (n << 4) + l15;
            bf16x4 pv;
#pragma unroll
            for (int r = 0; r < 4; ++r) pv[r] = (__bf16)acc[2][j][n][r];
            const int trow0 = tb + (g << 2);
            *reinterpret_cast<bf16x4*>(lds + VT_OFF + hcol * 512 + ((2 * trow0) ^ ((hcol & 7) << 4))) = pv;
#pragma unroll
            for (int r = 0; r < 4; ++r) {
                const int trow = trow0 + r;
                *reinterpret_cast<__bf16*>(lds + KS_OFF + trow * 128 + ((2 * hcol) ^ ((trow & 7) << 4))) =
                    (__bf16)acc[1][j][n][r];
            }
        }
        // Q tile j through wave-local scratch -> A-frags
#pragma unroll
        for (int n = 0; n < 4; ++n)
#pragma unroll
            for (int r = 0; r < 4; ++r) {
                const int row = (g << 2) + r;
                *reinterpret_cast<__bf16*>(
                    scr + row * 128 + ((2 * ((n << 4) + l15)) ^ ((row & 7) << 4))) = (__bf16)acc[0][j][n][r];
            }
        qf[j][0] = *reinterpret_cast<const bf16x8*>(
            scr + l15 * 128 + (((g << 4) + 0) ^ ((l15 & 7) << 4)));
        qf[j][1] = *reinterpret_cast<const bf16x8*>(
            scr + l15 * 128 + (((g << 4) + 64) ^ ((l15 & 7) << 4)));
    }
    __syncthreads();   // Ks/VT visible to all; XS/WF regions now retired

    // ---------------- Phase 2: causal attention (no barriers) ----------------
    const float se = 0.051031036307982884f * 1.4426950408889634f;  // 384^-0.5 * log2(e)

    auto attend = [&](int mt, bf16x8 qfa, bf16x8 qfb) {
        const int mtu = __builtin_amdgcn_readfirstlane(mt);
        const int q0  = mt << 4;
        const int qrow = q0 + (g << 2);

        f32x4 o[4];
#pragma unroll
        for (int nh = 0; nh < 4; ++nh) o[nh] = (f32x4){0.f, 0.f, 0.f, 0.f};
        float ssum[4] = {0.f, 0.f, 0.f, 0.f};

#pragma unroll
        for (int kc = 0; kc < 4; ++kc) {
            if (kc <= (mtu >> 2)) {     // wave-uniform causal skip
                f32x4 sb[4];
#pragma unroll
                for (int n4 = 0; n4 < 4; ++n4) sb[n4] = (f32x4){0.f, 0.f, 0.f, 0.f};
#pragma unroll
                for (int ks4 = 0; ks4 < 2; ++ks4) {
                    const bf16x8 qv = (ks4 == 0) ? qfa : qfb;
#pragma unroll
                    for (int n4 = 0; n4 < 4; ++n4) {
                        const int brow = (kc << 6) + (n4 << 4) + l15;
                        const bf16x8 bfr = *reinterpret_cast<const bf16x8*>(
                            lds + KS_OFF + brow * 128 + (((ks4 << 6) + (g << 4)) ^ ((brow & 7) << 4)));
                        sb[n4] = __builtin_amdgcn_mfma_f32_16x16x32_bf16(qv, bfr, sb[n4], 0, 0, 0);
                    }
                }
                // p = exp(s*scale); no max-sub (normalization cancels, |s*scale| small). mask, stage.
#pragma unroll
                for (int n4 = 0; n4 < 4; ++n4) {
                    const int k = (kc << 6) + (n4 << 4) + l15;
#pragma unroll
                    for (int r = 0; r < 4; ++r) {
                        float p = exp2f(sb[n4][r] * se);
                        if (k > qrow + r) p = 0.f;
                        ssum[r] += p;
                        const int prow = (g << 2) + r;
                        *reinterpret_cast<__bf16*>(
                            scr + prow * 128 + ((2 * ((n4 << 4) + l15)) ^ ((prow & 7) << 4))) = (__bf16)p;
                    }
                }
#pragma unroll
                for (int ks4 = 0; ks4 < 2; ++ks4) {
                    const bf16x8 pf = *reinterpret_cast<const bf16x8*>(
                        scr + l15 * 128 + (((ks4 << 6) + (g << 4)) ^ ((l15 & 7) << 4)));
#pragma unroll
                    for (int nh = 0; nh < 4; ++nh) {
                        const int hrow = (nh << 4) + l15;
                        const bf16x8 vb = *reinterpret_cast<const bf16x8*>(
                            lds + VT_OFF + hrow * 512 +
                            (((kc << 7) + (ks4 << 6) + (g << 4)) ^ ((hrow & 7) << 4)));
                        o[nh] = __builtin_amdgcn_mfma_f32_16x16x32_bf16(pf, vb, o[nh], 0, 0, 0);
                    }
                }
            }
        }

#pragma unroll
        for (int d = 1; d < 16; d <<= 1)
#pragma unroll
            for (int r = 0; r < 4; ++r)
                ssum[r] += __shfl_xor(ssum[r], d);

        float inv[4];
#pragma unroll
        for (int r = 0; r < 4; ++r) inv[r] = 1.0f / ssum[r];
        float* ob = out + ((size_t)b * T + q0) * H;
#pragma unroll
        for (int nh = 0; nh < 4; ++nh)
#pragma unroll
            for (int r = 0; r < 4; ++r)
                ob[((g << 2) + r) * H + (nh << 4) + l15] = o[nh][r] * inv[r];
    };

    attend(tile0, qf[0][0], qf[0][1]);
    attend(tile1, qf[1][0], qf[1][1]);
}

extern "C" void kernel_launch(void* const* d_in, const int* in_sizes, int n_in,
                              void* d_out, int out_size, void* d_ws, size_t ws_size,
                              hipStream_t stream) {
    (void)in_sizes; (void)n_in; (void)out_size;
    const float* x  = (const float*)d_in[0];
    const float* Wk = (const float*)d_in[1];
    const float* Wq = (const float*)d_in[2];
    const float* Wv = (const float*)d_in[3];
    float* out = (float*)d_out;
    const size_t wt_bytes = (size_t)9216 * 8 * sizeof(__bf16);
    if (ws_size >= wt_bytes) {
        __bf16* wT = (__bf16*)d_ws;
        prep_w<<<dim3(36), dim3(256), 0, stream>>>(Wq, Wk, Wv, wT);
        head_fused<true><<<dim3(BATCH), dim3(512), 0, stream>>>(x, Wq, Wk, Wv, wT, out);
    } else {
        head_fused<false><<<dim3(BATCH), dim3(512), 0, stream>>>(x, Wq, Wk, Wv, nullptr, out);
    }
}